// Round 1
// baseline (228.682 us; speedup 1.0000x reference)
//
#include <hip/hip_runtime.h>

// Shapes (fixed for this problem instance)
//   msa  [1,128,256,256] fp32   pair [1,256,256,128] fp32
//   w_left/w_right [256,32], w_out [1024,128], out [1,256,256,128] fp32
// ws layout: leftT [256][32][128] bf16 (2MB) | rightT same (2MB) | w2 [16][128][64] bf16 (256KB)

typedef float v4f __attribute__((ext_vector_type(4)));
typedef short v8s __attribute__((ext_vector_type(8)));

static __device__ inline unsigned short f2bf(float x) {
    unsigned int u = __builtin_bit_cast(unsigned int, x);
    return (unsigned short)((u + 0x7fffu + ((u >> 16) & 1u)) >> 16);
}

// ---------------- w_out transpose: w2[ck][p][kc], k = ck*64+kc ----------------
__global__ __launch_bounds__(256) void k_prep(const float* __restrict__ w_out,
                                              unsigned short* __restrict__ w2) {
    __shared__ unsigned short lds[32 * 72];   // [32 p][64 k + 8 pad]
    const int t = threadIdx.x;
    const int k0 = blockIdx.x * 64, p0 = blockIdx.y * 32;
    for (int it = 0; it < 8; ++it) {
        int e = it * 256 + t;                 // 0..2047
        int k = e >> 5, p = e & 31;           // coalesced read (p contiguous)
        lds[p * 72 + k] = f2bf(w_out[(k0 + k) * 128 + p0 + p]);
    }
    __syncthreads();
    int p = t >> 3, off = (t & 7) * 8;        // 256 chunks of 8 bf16 (16B)
    uint4 v = *(const uint4*)&lds[p * 72 + off];
    int ck = k0 >> 6;                          // k0 is 64-aligned
    *(uint4*)&w2[ck * 8192 + (p0 + p) * 64 + off] = v;
}

// ---------------- LayerNorm + left/right projection (MFMA) ----------------
// grid (256 l, 4 s-quarters), block 256. Output leftT[l][i][s], rightT[l][j][s] bf16.
__global__ __launch_bounds__(256) void k_lnproj(
    const float* __restrict__ msa, const float* __restrict__ gamma, const float* __restrict__ beta,
    const float* __restrict__ wl, const float* __restrict__ bl,
    const float* __restrict__ wr, const float* __restrict__ br,
    unsigned short* __restrict__ leftT, unsigned short* __restrict__ rightT) {
    __shared__ unsigned short xb[32 * 264];    // [32 s][256 d + 8 pad] bf16
    __shared__ unsigned short wT[64 * 264];    // [64 c][256 d + 8 pad] bf16 (c<32: left, else right)
    __shared__ unsigned short outT[64 * 40];   // [64 c][32 s + 8 pad] bf16

    const int t = threadIdx.x, lane = t & 63, w = t >> 6;
    const int l = blockIdx.x, s0 = blockIdx.y * 32;
    const int quad = lane >> 4, l15 = lane & 15;

    // stage W (coalesced global fp32 -> scalar LDS bf16, transposed)
    for (int it = 0; it < 64; ++it) {
        int e = it * 256 + t;                  // 0..16383
        int half = e >> 13;
        int e2 = e & 8191;
        int d = e2 >> 5, c = (e2 & 31) + half * 32;
        float v = half ? wr[e2] : wl[e2];
        wT[c * 264 + d] = f2bf(v);
    }

    // LayerNorm: each wave does 8 rows
    float4 g4 = *(const float4*)&gamma[lane * 4];
    float4 be4 = *(const float4*)&beta[lane * 4];
    for (int r = 0; r < 8; ++r) {
        int sl = w * 8 + r;
        int s = s0 + sl;
        const float* row = msa + (size_t)(s * 256 + l) * 256;
        float4 v = *(const float4*)&row[lane * 4];
        float sum = v.x + v.y + v.z + v.w;
        float sq = v.x * v.x + v.y * v.y + v.z * v.z + v.w * v.w;
        for (int o = 32; o > 0; o >>= 1) { sum += __shfl_xor(sum, o); sq += __shfl_xor(sq, o); }
        float mu = sum * (1.f / 256);
        float rs = rsqrtf(sq * (1.f / 256) - mu * mu + 1e-5f);
        ushort4 xs;
        xs.x = f2bf((v.x - mu) * rs * g4.x + be4.x);
        xs.y = f2bf((v.y - mu) * rs * g4.y + be4.y);
        xs.z = f2bf((v.z - mu) * rs * g4.z + be4.z);
        xs.w = f2bf((v.w - mu) * rs * g4.w + be4.w);
        *(ushort4*)&xb[sl * 264 + lane * 4] = xs;
    }
    __syncthreads();

    // MFMA: M=32 (s), N=64 (c), K=256. wave w: M-tile w>>1, N-tiles (w&1)*2 + {0,1}
    const int mt = w >> 1, ntb = (w & 1) * 2;
    v4f acc[2] = {};
    const int frow = (mt * 16 + l15) * 264;
    for (int ks = 0; ks < 8; ++ks) {
        int k = ks * 32 + quad * 8;
        v8s a = *(const v8s*)&xb[frow + k];
        v8s b0 = *(const v8s*)&wT[(ntb * 16 + l15) * 264 + k];
        v8s b1 = *(const v8s*)&wT[((ntb + 1) * 16 + l15) * 264 + k];
        acc[0] = __builtin_amdgcn_mfma_f32_16x16x32_bf16(a, b0, acc[0], 0, 0, 0);
        acc[1] = __builtin_amdgcn_mfma_f32_16x16x32_bf16(a, b1, acc[1], 0, 0, 0);
    }

    // epilogue: bias (+ 1/N scale for right), bf16, transpose via LDS
    for (int tn = 0; tn < 2; ++tn) {
        int c = (ntb + tn) * 16 + l15;
        float bias = c < 32 ? bl[c] : br[c - 32];
        float scale = c < 32 ? 1.f : (1.f / 128);
        for (int r = 0; r < 4; ++r) {
            int sl = mt * 16 + quad * 4 + r;
            outT[c * 40 + sl] = f2bf((acc[tn][r] + bias) * scale);
        }
    }
    __syncthreads();

    // coalesced 16B global writes: leftT[l][c][s0+off..], rightT[l][c-32][s0+off..]
    {
        int c = t >> 2, off = (t & 3) * 8;
        uint4 vv = *(const uint4*)&outT[c * 40 + off];
        unsigned short* dst = (c < 32) ? (leftT + l * 4096 + c * 128)
                                       : (rightT + l * 4096 + (c - 32) * 128);
        *(uint4*)&dst[s0 + off] = vv;
    }
}

// ---------------- fused outer-product + w_out projection ----------------
// grid (64,64): block covers l0..l0+3 x m0..m0+3. block 256 threads (4 waves, 2x2).
__global__ __launch_bounds__(256) void k_outer(
    const unsigned short* __restrict__ leftT, const unsigned short* __restrict__ rightT,
    const unsigned short* __restrict__ w2, const float* __restrict__ bout,
    const float* __restrict__ pairIn, float* __restrict__ out) {
    __shared__ alignas(16) unsigned char smem[55296];
    unsigned short* Ah   = (unsigned short*)smem;             // [128][72] phase A
    unsigned short* Bh   = (unsigned short*)(smem + 18432);   // [128][72] phase A
    unsigned short* Obuf = (unsigned short*)smem;             // [16][1032] phase B (33024B)
    unsigned short* wlds = (unsigned short*)(smem + 36864);   // [128][72] phase B (18432B)

    const int t = threadIdx.x, lane = t & 63, w = t >> 6;
    const int l0 = blockIdx.x * 4, m0 = blockIdx.y * 4;
    const int wm = w & 1, wn = w >> 1;
    const int quad = lane >> 4, l15 = lane & 15;

    const unsigned short* Asrc = leftT + l0 * 4096;   // [4 l][32 i][128 s] contiguous
    const unsigned short* Bsrc = rightT + m0 * 4096;

    // ---- phase A: O[128x128] = A[128x128(K=s)] * B^T, K split into 2 halves of 64
    v4f acc[4][4] = {};
    for (int kh = 0; kh < 2; ++kh) {
        __syncthreads();
        for (int it = 0; it < 4; ++it) {
            int el = (it * 256 + t) * 8;
            int m = el >> 6, off = el & 63;
            *(uint4*)&Ah[m * 72 + off] = *(const uint4*)&Asrc[m * 128 + kh * 64 + off];
            *(uint4*)&Bh[m * 72 + off] = *(const uint4*)&Bsrc[m * 128 + kh * 64 + off];
        }
        __syncthreads();
        for (int ks = 0; ks < 2; ++ks) {
            int k = ks * 32 + quad * 8;
            v8s a[4], b[4];
            for (int i = 0; i < 4; ++i) a[i] = *(const v8s*)&Ah[(wm * 64 + i * 16 + l15) * 72 + k];
            for (int j = 0; j < 4; ++j) b[j] = *(const v8s*)&Bh[(wn * 64 + j * 16 + l15) * 72 + k];
            for (int i = 0; i < 4; ++i)
                for (int j = 0; j < 4; ++j)
                    acc[i][j] = __builtin_amdgcn_mfma_f32_16x16x32_bf16(a[i], b[j], acc[i][j], 0, 0, 0);
        }
    }
    __syncthreads();   // all phase-A LDS reads done before Obuf overwrites Ah/Bh

    // ---- scatter acc -> Obuf[pair][i*32+j] bf16
    for (int i = 0; i < 4; ++i)
        for (int j = 0; j < 4; ++j)
            for (int r = 0; r < 4; ++r) {
                int grow = wm * 64 + i * 16 + quad * 4 + r;   // (dl, i)
                int gcol = wn * 64 + j * 16 + l15;            // (dm, j)
                int dl = grow >> 5, ii = grow & 31;
                int dm = gcol >> 5, jj = gcol & 31;
                Obuf[(dl * 4 + dm) * 1032 + ii * 32 + jj] = f2bf(acc[i][j][r]);
            }

    // ---- phase B: P[16][128] = Obuf[16][1024] @ w_out[1024][128], K chunks of 64
    v4f acc2[2] = {};
    for (int ck = 0; ck < 16; ++ck) {
        __syncthreads();   // ck=0: guards Obuf writes; ck>0: guards prev wlds reads
        for (int it = 0; it < 4; ++it) {
            int el = (it * 256 + t) * 8;
            *(uint4*)&wlds[(el >> 6) * 72 + (el & 63)] = *(const uint4*)&w2[ck * 8192 + el];
        }
        __syncthreads();
        for (int inner = 0; inner < 2; ++inner) {
            int kk = inner * 32 + quad * 8;
            v8s a = *(const v8s*)&Obuf[l15 * 1032 + ck * 64 + kk];
            for (int tt = 0; tt < 2; ++tt) {
                int p = (w * 2 + tt) * 16 + l15;
                v8s b = *(const v8s*)&wlds[p * 72 + kk];
                acc2[tt] = __builtin_amdgcn_mfma_f32_16x16x32_bf16(a, b, acc2[tt], 0, 0, 0);
            }
        }
    }

    // ---- epilogue: out = pair + P + b_out
    for (int tt = 0; tt < 2; ++tt) {
        int p = (w * 2 + tt) * 16 + l15;
        float bo = bout[p];
        for (int r = 0; r < 4; ++r) {
            int pr = quad * 4 + r;               // pair index 0..15
            int dl = pr >> 2, dm = pr & 3;
            size_t idx = (size_t)((l0 + dl) * 256 + (m0 + dm)) * 128 + p;
            out[idx] = pairIn[idx] + bo + acc2[tt][r];
        }
    }
}

extern "C" void kernel_launch(void* const* d_in, const int* in_sizes, int n_in,
                              void* d_out, int out_size, void* d_ws, size_t ws_size,
                              hipStream_t stream) {
    const float* msa   = (const float*)d_in[0];
    const float* pairI = (const float*)d_in[1];
    // d_in[2], d_in[3]: symmids/symmsub (unused by reference)
    const float* gamma = (const float*)d_in[4];
    const float* beta  = (const float*)d_in[5];
    const float* wl    = (const float*)d_in[6];
    const float* bl    = (const float*)d_in[7];
    const float* wr    = (const float*)d_in[8];
    const float* br    = (const float*)d_in[9];
    const float* wout  = (const float*)d_in[10];
    const float* bout  = (const float*)d_in[11];
    float* out = (float*)d_out;

    unsigned short* leftT  = (unsigned short*)d_ws;                 // 1,048,576 el
    unsigned short* rightT = leftT + 256 * 32 * 128;                // 1,048,576 el
    unsigned short* w2     = rightT + 256 * 32 * 128;               // 131,072 el

    k_prep<<<dim3(16, 4), 256, 0, stream>>>(wout, w2);
    k_lnproj<<<dim3(256, 4), 256, 0, stream>>>(msa, gamma, beta, wl, bl, wr, br, leftT, rightT);
    k_outer<<<dim3(64, 64), 256, 0, stream>>>(leftT, rightT, w2, bout, pairI, out);
}